// Round 10
// baseline (374.344 us; speedup 1.0000x reference)
//
#include <hip/hip_runtime.h>
#include <hip/hip_cooperative_groups.h>
#include <hip/hip_fp16.h>

namespace cg = cooperative_groups;

#define EPS 0.1f
#define SINK_ITERS 50
#define KSCALE_LN 9.0109133472f   /* 13*ln2 : K scaled by 2^13 into f16 normal range */
#define CAND_CAP 4096

typedef _Float16 f16;
typedef _Float16 f16x4 __attribute__((ext_vector_type(4)));
typedef _Float16 f16x8 __attribute__((ext_vector_type(8)));
typedef float f32x4 __attribute__((ext_vector_type(4)));

#define PIN_U4(v) asm volatile("" : "+v"(v.x), "+v"(v.y), "+v"(v.z), "+v"(v.w))

__device__ __forceinline__ float wave_red_sum(float v) {
    #pragma unroll
    for (int o = 32; o; o >>= 1) v += __shfl_xor(v, o, 64);
    return v;
}

// LDS union for the pre kernel
union __align__(16) SM {
    struct { f16 Ai[64 * 40]; f16 Bj[64 * 40]; } g;   // gemm stage (10240 B)
    struct { float a[8]; float b[8]; } r;             // pre reductions
    struct { int redc[8]; int binsel[2]; int krel[2]; float mres[2]; } m; // median scan/select
    float red[8];                                     // prep reductions
};

__device__ __forceinline__ int med_bin(float v) {
    int b = (int)(v * 4096.f);
    if (v < (float)b * (1.f / 4096.f)) b--;
    else if (v >= (float)(b + 1) * (1.f / 4096.f)) b++;
    if (b < 0) b = 0;
    if (b > 8191) b = 8191;
    return b;
}

// ---- one 64x64 Gram tile over a 256-wide k slab (8 chunks of 32), 8 waves ----
__device__ __forceinline__ void gemm_unit(const uint4* __restrict__ X, int lda8,
                                          int i0, int j0, int kb8_0,
                                          float* __restrict__ out, SM& sm, int t) {
    int lane = t & 63, wv = t >> 6, m16 = lane & 15, quad = lane >> 4;
    int rr = (t & 255) >> 2, kk = t & 3;
    int rbase = (t < 256) ? i0 : j0;
    f16* stg = (t < 256) ? sm.g.Ai : sm.g.Bj;
    f32x4 a0 = {0.f, 0.f, 0.f, 0.f}, a1 = {0.f, 0.f, 0.f, 0.f};
    for (int ch = 0; ch < 8; ch++) {
        uint4 v = X[(size_t)(rbase + rr) * lda8 + kb8_0 + ch * 4 + kk];
        __syncthreads();
        *(uint4*)&stg[rr * 40 + kk * 8] = v;
        __syncthreads();
        f16x8 a  = *(const f16x8*)&sm.g.Ai[((wv & 3) * 16 + m16) * 40 + quad * 8];
        f16x8 b0 = *(const f16x8*)&sm.g.Bj[((wv >> 2) * 32 + m16) * 40 + quad * 8];
        f16x8 b1 = *(const f16x8*)&sm.g.Bj[((wv >> 2) * 32 + 16 + m16) * 40 + quad * 8];
        a0 = __builtin_amdgcn_mfma_f32_16x16x32_f16(a, b0, a0, 0, 0, 0);
        a1 = __builtin_amdgcn_mfma_f32_16x16x32_f16(a, b1, a1, 0, 0, 0);
    }
    int orow = i0 + (wv & 3) * 16 + quad * 4;
    int ocol = j0 + (wv >> 2) * 32 + m16;
    #pragma unroll
    for (int reg = 0; reg < 4; reg++) {
        out[(orow + reg) * 256 + ocol] = a0[reg];
        out[(orow + reg) * 256 + ocol + 16] = a1[reg];
    }
}

// ---- prep row helpers ----
__device__ __forceinline__ void prep_a_row(int row, int t, SM& sm,
                                           const float* __restrict__ part2,
                                           const float* __restrict__ Do,
                                           const float* __restrict__ lsl,
                                           float* __restrict__ Pl, float* __restrict__ ELl,
                                           f16* __restrict__ Kh) {
    float x = lsl[0];
    float sp = (x > 20.f) ? x : log1pf(__expf(x));
    float sgl = sp + 1e-6f;
    float i2l = 1.f / (2.f * sgl * sgl);
    float slv = 0.f, dov = 0.f;
    if (t < 256) {
        int e = row * 256 + t;
        float dl = fmaxf(1.f - part2[e], 0.f);
        slv = (row == t) ? 0.f : __expf(-dl * dl * i2l);
        dov = Do[e];
    }
    float ws = wave_red_sum(slv);
    if ((t & 63) == 0) sm.red[t >> 6] = ws;
    __syncthreads();
    float tot = sm.red[0] + sm.red[1] + sm.red[2] + sm.red[3];
    if (t < 256) {
        int e = row * 256 + t;
        float pl = slv / fmaxf(tot, 1e-8f);
        Pl[e] = pl;
        ELl[e] = EPS * __logf(fmaxf(pl, 1e-8f));
        float kv = __expf(-dov * (1.f / EPS) + KSCALE_LN);
        Kh[(((row >> 3) * 256 + t) << 3) + (row & 7)] = (f16)kv;
    }
    __syncthreads();
}

__device__ __forceinline__ void prep_b_row(int row, int t, SM& sm,
                                           const float* __restrict__ Do,
                                           const float* __restrict__ acc,
                                           float* __restrict__ Po, float* __restrict__ ELo) {
    float sg = acc[4];
    if (sg == 0.f) sg = 1e-6f;
    float i2o = 1.f / (2.f * sg * sg);
    float sov = 0.f;
    if (t < 256) {
        float dov = Do[row * 256 + t];
        sov = (row == t) ? 0.f : __expf(-dov * dov * i2o);
    }
    float ws = wave_red_sum(sov);
    if ((t & 63) == 0) sm.red[t >> 6] = ws;
    __syncthreads();
    float tot = sm.red[0] + sm.red[1] + sm.red[2] + sm.red[3];
    if (t < 256) {
        int e = row * 256 + t;
        float po = sov / fmaxf(tot, 1e-8f);
        Po[e] = po;
        ELo[e] = EPS * __logf(fmaxf(po, 1e-8f));
    }
    __syncthreads();
}

// ================= cooperative pre kernel: P0..P5 =================
__global__ __launch_bounds__(512, 1) void k_pre_coop(const float4* __restrict__ xo4,
                                                     const float4* __restrict__ xr4,
                                                     const float4* __restrict__ z4,
                                                     const float* __restrict__ lsl,
                                                     float* __restrict__ ws) {
    cg::grid_group grid = cg::this_grid();
    __shared__ SM sm;
    const int b = blockIdx.x, t = threadIdx.x;
    const int lane = t & 63, wv = t >> 6;

    float* acc = ws;                          // [0..2] ot, [3] recon, [4] sigma
    int* hist = (int*)(ws + 64);              // 8192 bins
    int* cnt = (int*)(ws + 8256);             // 2 counters
    float* candA = ws + 8320;                 // CAND_CAP
    float* candB = ws + 8320 + CAND_CAP;      // CAND_CAP
    f16* xh = (f16*)(ws + 16512);
    f16* zh = xh + 1048576;
    float* Do = (float*)(zh + 65536);
    float* Po = Do + 65536;
    float* Pl = Po + 65536;
    float* ELo = Pl + 65536;
    float* ELl = ELo + 65536;
    f16* Kh = (f16*)(ELl + 65536);
    float* part = (float*)(Kh + 65536);
    float* part2 = part + 16 * 65536;

    // ---------- P0: recon + normalize ----------
    {
        if (t < 64) {
            float4 vz = z4[(size_t)b * 64 + t];
            float sz = vz.x * vz.x + vz.y * vz.y + vz.z * vz.z + vz.w * vz.w;
            sz = wave_red_sum(sz);
            float rnz = 1.f / sqrtf(fmaxf(sz, 1e-8f));
            f16x4 h;
            h[0] = (f16)(vz.x * rnz); h[1] = (f16)(vz.y * rnz);
            h[2] = (f16)(vz.z * rnz); h[3] = (f16)(vz.w * rnz);
            *(f16x4*)&zh[(size_t)b * 256 + t * 4] = h;
        }
        size_t ro = (size_t)b * 1024;
        float4 v0 = xo4[ro + t], v1 = xo4[ro + t + 512];
        float4 r0 = xr4[ro + t], r1 = xr4[ro + t + 512];
        float sq = v0.x * v0.x + v0.y * v0.y + v0.z * v0.z + v0.w * v0.w
                 + v1.x * v1.x + v1.y * v1.y + v1.z * v1.z + v1.w * v1.w;
        float d0 = r0.x - v0.x, d1 = r0.y - v0.y, d2 = r0.z - v0.z, d3 = r0.w - v0.w;
        float e0 = r1.x - v1.x, e1 = r1.y - v1.y, e2 = r1.z - v1.z, e3 = r1.w - v1.w;
        float rs = d0 * d0 + d1 * d1 + d2 * d2 + d3 * d3
                 + e0 * e0 + e1 * e1 + e2 * e2 + e3 * e3;
        float wq = wave_red_sum(sq), wr = wave_red_sum(rs);
        if (lane == 0) { sm.r.a[wv] = wq; sm.r.b[wv] = wr; }
        __syncthreads();
        float tq = 0.f, tr = 0.f;
        #pragma unroll
        for (int i = 0; i < 8; i++) { tq += sm.r.a[i]; tr += sm.r.b[i]; }
        if (t == 0) atomicAdd(acc + 3, tr);
        float rn = 1.f / sqrtf(fmaxf(tq, 1e-8f));
        f16x4 h0, h1;
        h0[0] = (f16)(v0.x * rn); h0[1] = (f16)(v0.y * rn);
        h0[2] = (f16)(v0.z * rn); h0[3] = (f16)(v0.w * rn);
        h1[0] = (f16)(v1.x * rn); h1[1] = (f16)(v1.y * rn);
        h1[2] = (f16)(v1.z * rn); h1[3] = (f16)(v1.w * rn);
        *(f16x4*)&xh[(size_t)b * 4096 + t * 4] = h0;
        *(f16x4*)&xh[(size_t)b * 4096 + 2048 + t * 4] = h1;
    }
    grid.sync();

    // ---------- P1: Gram GEMMs ----------
    {
        int tile = b >> 4, slab = b & 15;
        gemm_unit((const uint4*)xh, 512, (tile >> 2) * 64, (tile & 3) * 64,
                  slab * 32, part + (size_t)slab * 65536, sm, t);
        if (b >= 240) {
            int tl = b - 240;
            gemm_unit((const uint4*)zh, 32, (tl >> 2) * 64, (tl & 3) * 64, 0, part2, sm, t);
        }
    }
    grid.sync();

    // ---------- P2: Do + global histogram ----------
    if (t < 256) {
        int e = b * 256 + t;
        float s = 0.f;
        for (int sl = 0; sl < 16; sl++) s += part[(size_t)sl * 65536 + e];
        float dv = fmaxf(1.f - s, 0.f);
        Do[e] = dv;
        atomicAdd(&hist[med_bin(dv)], 1);
    }
    grid.sync();

    // ---------- P3: hist scan (all blocks, redundant) + candidate append + prep_a ----------
    int bin0, bin1, kr0, kr1;
    {
        int chunk = t * 16;
        int s16 = 0;
        #pragma unroll
        for (int j = 0; j < 16; j++) s16 += hist[chunk + j];
        int inc = s16;
        #pragma unroll
        for (int o = 1; o < 64; o <<= 1) {
            int vv = __shfl_up(inc, o, 64);
            if (lane >= o) inc += vv;
        }
        if (lane == 63) sm.m.redc[wv] = inc;
        __syncthreads();
        int woff = 0;
        for (int i = 0; i < wv; i++) woff += sm.m.redc[i];
        int excl = woff + inc - s16;
        for (int sel = 0; sel < 2; sel++) {
            int k = 32767 + sel;
            if (excl <= k && k < excl + s16) {
                int cum = excl;
                bool found = false;
                for (int j = 0; j < 16; j++) {
                    int hc = hist[chunk + j];
                    if (!found) {
                        if (cum + hc > k) { sm.m.binsel[sel] = chunk + j; sm.m.krel[sel] = k - cum; found = true; }
                        else cum += hc;
                    }
                }
            }
        }
        __syncthreads();
        bin0 = sm.m.binsel[0]; bin1 = sm.m.binsel[1];
        kr0 = sm.m.krel[0];    kr1 = sm.m.krel[1];
        __syncthreads();   // release union before prep_a clobbers it
        if (t < 256) {
            float dv = Do[b * 256 + t];
            int bb = med_bin(dv);
            if (bb == bin0) {
                int ix = atomicAdd(&cnt[0], 1);
                if (ix < CAND_CAP) candA[ix] = dv;
            }
            if (bb == bin1) {
                int ix = atomicAdd(&cnt[1], 1);
                if (ix < CAND_CAP) candB[ix] = dv;
            }
        }
        prep_a_row(b, t, sm, part2, Do, lsl, Pl, ELl, Kh);
    }
    grid.sync();

    // ---------- P4: block 0 exact selection-by-counting ----------
    if (b == 0) {
        if (t == 0) {   // overflow fallback: bin midpoints
            sm.m.mres[0] = ((float)bin0 + 0.5f) * (1.f / 4096.f);
            sm.m.mres[1] = ((float)bin1 + 0.5f) * (1.f / 4096.f);
        }
        __syncthreads();
        int M0 = cnt[0] < CAND_CAP ? cnt[0] : 0;   // 0 => keep fallback
        int M1 = cnt[1] < CAND_CAP ? cnt[1] : 0;
        for (int ci = t; ci < M0; ci += 512) {
            float x = candA[ci];
            int L = 0, E = 0;
            for (int j = 0; j < M0; j++) {
                float v = candA[j];
                L += (v < x) ? 1 : 0;
                E += (v == x) ? 1 : 0;
            }
            if (L <= kr0 && kr0 < L + E) sm.m.mres[0] = x;
        }
        for (int ci = t; ci < M1; ci += 512) {
            float x = candB[ci];
            int L = 0, E = 0;
            for (int j = 0; j < M1; j++) {
                float v = candB[j];
                L += (v < x) ? 1 : 0;
                E += (v == x) ? 1 : 0;
            }
            if (L <= kr1 && kr1 < L + E) sm.m.mres[1] = x;
        }
        __syncthreads();
        if (t == 0) acc[4] = 0.5f * (sm.m.mres[0] + sm.m.mres[1]);
    }
    grid.sync();

    // ---------- P5: prep_b ----------
    prep_b_row(b, t, sm, Do, acc, Po, ELo);
}

// ================= Sinkhorn: 256 blocks x 512 thr, P=3 problems/block =================
// Loop-live registers minimized: only the pinned K fragment (64 VGPR) + MFMA accs
// stay live; EL consts, F/G duals, and Z all round-trip through LDS. ZP is [p][c]
// (phase-B reads conflict-free); FG written only on the last two steps.
__global__ __launch_bounds__(512, 2) void k_sink(const float* __restrict__ Po,
                                                 const float* __restrict__ Pl,
                                                 const float* __restrict__ ELo,
                                                 const float* __restrict__ ELl,
                                                 const uint4* __restrict__ Kq,
                                                 float* __restrict__ acc) {
    __shared__ __align__(16) f16 U[4 * 272];      // rows 0..2 live, row 3 dummy 1.0
    __shared__ float ZP[4][256];                  // [p][c], p=3 junk
    __shared__ float ELC[2][3][256];              // [fs][p][c]: fs=1 f-step (a), fs=0 g-step (b)
    __shared__ float FG[2][3][256];               // [fs][p][c]: FG[1]=f, FG[0]=g
    __shared__ float CW[8], CWb[4];
    int t = threadIdx.x;
    int lane = t & 63, wv = t >> 6, m16 = lane & 15, quad = lane >> 4;
    int b = blockIdx.x;
    int pA = t >> 8, cAv = t & 255;

    // K fragments: wave wv owns cols [32wv, 32wv+32) as two 16-col subtiles
    uint4 bf0[8], bf1[8];
    int cA = 32 * wv + m16, cB = cA + 16;
    #pragma unroll
    for (int kc = 0; kc < 8; kc++) {
        bf0[kc] = Kq[(kc * 4 + quad) * 256 + cA];
        bf1[kc] = Kq[(kc * 4 + quad) * 256 + cB];
    }
    #pragma unroll
    for (int kc = 0; kc < 8; kc++) { PIN_U4(bf0[kc]); PIN_U4(bf1[kc]); }

    // EL constants -> LDS (once)
    for (int idx = t; idx < 768; idx += 512) {
        int p = idx >> 8, c = idx & 255;
        int r = b * 3 + p, s = r >> 8, i = r & 255;
        ELC[1][p][c] = ((s == 1 ? ELl : ELo) + i * 256)[c] + EPS * KSCALE_LN;
        ELC[0][p][c] = ((s == 2 ? ELo : ELl) + i * 256)[c] + EPS * KSCALE_LN;
    }
    if (t < 136)
        *(uint4*)&U[t * 8] = make_uint4(0x3C003C00u, 0x3C003C00u, 0x3C003C00u, 0x3C003C00u);
    __syncthreads();

    for (int it = 0; it < 2 * SINK_ITERS; it++) {
        // phase A: Z = U x K via MFMA (all 8 waves)
        f32x4 acc0 = {0.f, 0.f, 0.f, 0.f}, acc1 = {0.f, 0.f, 0.f, 0.f};
        #pragma unroll
        for (int kc = 0; kc < 8; kc++) {
            f16x8 a = *(const f16x8*)&U[(m16 & 3) * 272 + kc * 32 + quad * 8];
            acc0 = __builtin_amdgcn_mfma_f32_16x16x32_f16(a, __builtin_bit_cast(f16x8, bf0[kc]), acc0, 0, 0, 0);
            acc1 = __builtin_amdgcn_mfma_f32_16x16x32_f16(a, __builtin_bit_cast(f16x8, bf1[kc]), acc1, 0, 0, 0);
        }
        if (quad == 0) {
            #pragma unroll
            for (int reg = 0; reg < 3; reg++) {   // p=3 never read
                ZP[reg][cA] = acc0[reg];
                ZP[reg][cB] = acc1[reg];
            }
        }
        __syncthreads();
        // phase B: dual update, distributed (768 values over 512 threads)
        {
            int fs = it & 1;
            float d0 = ELC[fs][pA][cAv] - EPS * __logf(ZP[pA][cAv]);
            U[pA * 272 + cAv] = (f16)__expf(d0);
            if (it >= 2 * SINK_ITERS - 2) FG[fs][pA][cAv] = d0;
            if (t < 256) {
                float d1 = ELC[fs][2][t] - EPS * __logf(ZP[2][t]);
                U[2 * 272 + t] = (f16)__expf(d1);
                if (it >= 2 * SINK_ITERS - 2) FG[fs][2][t] = d1;
            }
        }
        __syncthreads();
    }

    // cost epilogue (pointers recomputed post-loop; not live across the loop)
    int rA = b * 3 + pA, sA = rA >> 8, iA = rA & 255;
    const float* paA = (sA == 1 ? Pl : Po) + iA * 256;
    const float* pbA = (sA == 2 ? Po : Pl) + iA * 256;
    float csA = paA[cAv] * FG[1][pA][cAv] + pbA[cAv] * FG[0][pA][cAv];
    float csB = 0.f;
    if (t < 256) {
        int rB = b * 3 + 2, sB = rB >> 8, iB = rB & 255;
        const float* paB = (sB == 1 ? Pl : Po) + iB * 256;
        const float* pbB = (sB == 2 ? Po : Pl) + iB * 256;
        csB = paB[t] * FG[1][2][t] + pbB[t] * FG[0][2][t];
    }
    float vA = wave_red_sum(csA);
    float vB = wave_red_sum(csB);
    if (lane == 0) { CW[wv] = vA; if (wv < 4) CWb[wv] = vB; }
    __syncthreads();
    if (t < 3) {
        float s;
        if (t == 0) s = CW[0] + CW[1] + CW[2] + CW[3];
        else if (t == 1) s = CW[4] + CW[5] + CW[6] + CW[7];
        else s = CWb[0] + CWb[1] + CWb[2] + CWb[3];
        atomicAdd(&acc[(b * 3 + t) >> 8], s);
    }
}

// ---------------- finalize ----------------
__global__ void k_final(const float* __restrict__ acc, const float* __restrict__ lvr_p,
                        const float* __restrict__ lvt_p, float* __restrict__ out) {
    float recon = acc[3] * (1.f / (256.f * 4096.f));
    float ot0 = acc[0] * (1.f / 256.f);
    float ot1 = acc[1] * (1.f / 256.f);
    float ot2 = acc[2] * (1.f / 256.f);
    float topo = ot0 - 0.5f * ot1 - 0.5f * ot2;
    topo = topo > 0.f ? topo : 0.f;  // * TOPO_MULT (=1)
    float a = lvr_p[0], c = lvt_p[0];
    out[0] = 0.5f * __expf(-a) * recon + 0.5f * a +
             0.5f * __expf(-c) * topo + 0.5f * c;
    out[1] = recon;
    out[2] = topo;
}

extern "C" void kernel_launch(void* const* d_in, const int* in_sizes, int n_in,
                              void* d_out, int out_size, void* d_ws, size_t ws_size,
                              hipStream_t stream) {
    const float4* xo4 = (const float4*)d_in[0];
    const float4* xr4 = (const float4*)d_in[1];
    const float4* z4  = (const float4*)d_in[2];
    const float* lsl = (const float*)d_in[3];
    const float* lvr = (const float*)d_in[4];
    const float* lvt = (const float*)d_in[5];
    float* out = (float*)d_out;
    float* ws = (float*)d_ws;

    // ws layout (floats) — must match k_pre_coop
    float* acc = ws;
    f16* xh = (f16*)(ws + 16512);
    f16* zh = xh + 1048576;
    float* Do = (float*)(zh + 65536);
    float* Po = Do + 65536;
    float* Pl = Po + 65536;
    float* ELo = Pl + 65536;
    float* ELl = ELo + 65536;
    f16* Kh = (f16*)(ELl + 65536);

    // zero acc + hist + counters (cand buffers don't need zeroing)
    hipMemsetAsync(ws, 0, 8320 * sizeof(float), stream);

    void* kargs[] = {(void*)&xo4, (void*)&xr4, (void*)&z4, (void*)&lsl, (void*)&ws};
    hipLaunchCooperativeKernel((void*)k_pre_coop, dim3(256), dim3(512), kargs, 0, stream);

    k_sink<<<256, 512, 0, stream>>>(Po, Pl, ELo, ELl, (const uint4*)Kh, acc);
    k_final<<<1, 1, 0, stream>>>(acc, lvr, lvt, out);
}

// Round 11
// 278.766 us; speedup vs baseline: 1.3429x; 1.3429x over previous
//
#include <hip/hip_runtime.h>
#include <hip/hip_fp16.h>

#define EPS 0.1f
#define SINK_ITERS 50
#define KSCALE_LN 9.0109133472f   /* 13*ln2 : K scaled by 2^13 into f16 normal range */
#define CCAP 1536

typedef _Float16 f16;
typedef _Float16 f16x4 __attribute__((ext_vector_type(4)));
typedef _Float16 f16x8 __attribute__((ext_vector_type(8)));
typedef float f32x4 __attribute__((ext_vector_type(4)));

#define PIN_U4(v) asm volatile("" : "+v"(v.x), "+v"(v.y), "+v"(v.z), "+v"(v.w))

__device__ __forceinline__ float wave_red_sum(float v) {
    #pragma unroll
    for (int o = 32; o; o >>= 1) v += __shfl_xor(v, o, 64);
    return v;
}

__device__ __forceinline__ int med_bin(float v) {
    int b = (int)(v * 4096.f);
    if (v < (float)b * (1.f / 4096.f)) b--;
    else if (v >= (float)(b + 1) * (1.f / 4096.f)) b++;
    if (b < 0) b = 0;
    if (b > 8191) b = 8191;
    return b;
}

// ws layout (floats):
//  acc = ws[0..63]  ([0..2] ot, [3] recon, [4] sigma-unused, [8] done ctr as uint)
//  hist = ws+64 (8192 ints)
//  xh = ws+8320 (1048576 f16), zh = +524288 fl (65536 f16)
//  Do = ws+565376 (65536 fl), Kh = +65536 fl (65536 f16)
//  part = ws+663680 (16*65536 fl), part2 = +1048576 fl (65536 fl)
#define WS_HIST   64
#define WS_XH     8320
#define WS_ZH     532608
#define WS_DO     565376
#define WS_KH     630912
#define WS_PART   663680
#define WS_PART2  1712256

// ---------------- k_pre: recon partial + row-normalize to f16 (256 blocks x 512) ----------------
__global__ __launch_bounds__(512, 2) void k_pre(const float4* __restrict__ xo4,
                                                const float4* __restrict__ xr4,
                                                const float4* __restrict__ z4,
                                                float* __restrict__ ws) {
    __shared__ float ra[8], rb[8];
    int b = blockIdx.x, t = threadIdx.x;
    int lane = t & 63, wv = t >> 6;
    float* acc = ws;
    f16* xh = (f16*)(ws + WS_XH);
    f16* zh = (f16*)(ws + WS_ZH);

    if (t < 64) {
        float4 vz = z4[(size_t)b * 64 + t];
        float sz = vz.x * vz.x + vz.y * vz.y + vz.z * vz.z + vz.w * vz.w;
        sz = wave_red_sum(sz);
        float rnz = 1.f / sqrtf(fmaxf(sz, 1e-8f));
        f16x4 h;
        h[0] = (f16)(vz.x * rnz); h[1] = (f16)(vz.y * rnz);
        h[2] = (f16)(vz.z * rnz); h[3] = (f16)(vz.w * rnz);
        *(f16x4*)&zh[(size_t)b * 256 + t * 4] = h;
    }
    size_t ro = (size_t)b * 1024;
    float4 v0 = xo4[ro + t], v1 = xo4[ro + t + 512];
    float4 r0 = xr4[ro + t], r1 = xr4[ro + t + 512];
    float sq = v0.x * v0.x + v0.y * v0.y + v0.z * v0.z + v0.w * v0.w
             + v1.x * v1.x + v1.y * v1.y + v1.z * v1.z + v1.w * v1.w;
    float d0 = r0.x - v0.x, d1 = r0.y - v0.y, d2 = r0.z - v0.z, d3 = r0.w - v0.w;
    float e0 = r1.x - v1.x, e1 = r1.y - v1.y, e2 = r1.z - v1.z, e3 = r1.w - v1.w;
    float rs = d0 * d0 + d1 * d1 + d2 * d2 + d3 * d3
             + e0 * e0 + e1 * e1 + e2 * e2 + e3 * e3;
    float wq = wave_red_sum(sq), wr = wave_red_sum(rs);
    if (lane == 0) { ra[wv] = wq; rb[wv] = wr; }
    __syncthreads();
    float tq = 0.f, tr = 0.f;
    #pragma unroll
    for (int i = 0; i < 8; i++) { tq += ra[i]; tr += rb[i]; }
    if (t == 0) atomicAdd(acc + 3, tr);
    float rn = 1.f / sqrtf(fmaxf(tq, 1e-8f));
    f16x4 h0, h1;
    h0[0] = (f16)(v0.x * rn); h0[1] = (f16)(v0.y * rn);
    h0[2] = (f16)(v0.z * rn); h0[3] = (f16)(v0.w * rn);
    h1[0] = (f16)(v1.x * rn); h1[1] = (f16)(v1.y * rn);
    h1[2] = (f16)(v1.z * rn); h1[3] = (f16)(v1.w * rn);
    *(f16x4*)&xh[(size_t)b * 4096 + t * 4] = h0;
    *(f16x4*)&xh[(size_t)b * 4096 + 2048 + t * 4] = h1;
}

// ---------------- k_gemm: Gram tiles (272 blocks x 512). b<256 big (16 tiles x 16 slabs), ----------------
// b>=256 small (16 tiles, full k). 64x64 tile over 256-wide k slab, f16 MFMA.
struct SMg { f16 Ai[64 * 40]; f16 Bj[64 * 40]; };

__device__ __forceinline__ void gemm_unit(const uint4* __restrict__ X, int lda8,
                                          int i0, int j0, int kb8_0,
                                          float* __restrict__ out, SMg& sm, int t) {
    int lane = t & 63, wv = t >> 6, m16 = lane & 15, quad = lane >> 4;
    int rr = (t & 255) >> 2, kk = t & 3;
    int rbase = (t < 256) ? i0 : j0;
    f16* stg = (t < 256) ? sm.Ai : sm.Bj;
    f32x4 a0 = {0.f, 0.f, 0.f, 0.f}, a1 = {0.f, 0.f, 0.f, 0.f};
    for (int ch = 0; ch < 8; ch++) {
        uint4 v = X[(size_t)(rbase + rr) * lda8 + kb8_0 + ch * 4 + kk];
        __syncthreads();
        *(uint4*)&stg[rr * 40 + kk * 8] = v;
        __syncthreads();
        f16x8 a  = *(const f16x8*)&sm.Ai[((wv & 3) * 16 + m16) * 40 + quad * 8];
        f16x8 b0 = *(const f16x8*)&sm.Bj[((wv >> 2) * 32 + m16) * 40 + quad * 8];
        f16x8 b1 = *(const f16x8*)&sm.Bj[((wv >> 2) * 32 + 16 + m16) * 40 + quad * 8];
        a0 = __builtin_amdgcn_mfma_f32_16x16x32_f16(a, b0, a0, 0, 0, 0);
        a1 = __builtin_amdgcn_mfma_f32_16x16x32_f16(a, b1, a1, 0, 0, 0);
    }
    int orow = i0 + (wv & 3) * 16 + quad * 4;
    int ocol = j0 + (wv >> 2) * 32 + m16;
    #pragma unroll
    for (int reg = 0; reg < 4; reg++) {
        out[(orow + reg) * 256 + ocol] = a0[reg];
        out[(orow + reg) * 256 + ocol + 16] = a1[reg];
    }
}

__global__ __launch_bounds__(512, 2) void k_gemm(float* __restrict__ ws) {
    __shared__ SMg sm;
    int b = blockIdx.x, t = threadIdx.x;
    const uint4* xh8 = (const uint4*)(ws + WS_XH);
    const uint4* zh8 = (const uint4*)(ws + WS_ZH);
    float* part = ws + WS_PART;
    float* part2 = ws + WS_PART2;
    if (b < 256) {
        int tile = b >> 4, slab = b & 15;
        gemm_unit(xh8, 512, (tile >> 2) * 64, (tile & 3) * 64,
                  slab * 32, part + (size_t)slab * 65536, sm, t);
    } else {
        int tl = b - 256;
        gemm_unit(zh8, 32, (tl >> 2) * 64, (tl & 3) * 64, 0, part2, sm, t);
    }
}

// ---------------- k_mid: Do row + histogram + Kh row (256 blocks x 256) ----------------
__global__ __launch_bounds__(256, 4) void k_mid(float* __restrict__ ws) {
    int b = blockIdx.x, t = threadIdx.x;
    int* hist = (int*)(ws + WS_HIST);
    float* Do = ws + WS_DO;
    f16* Kh = (f16*)(ws + WS_KH);
    const float* part = ws + WS_PART;
    int e = b * 256 + t;
    float s = 0.f;
    for (int sl = 0; sl < 16; sl++) s += part[(size_t)sl * 65536 + e];
    float dv = fmaxf(1.f - s, 0.f);
    Do[e] = dv;
    atomicAdd(&hist[med_bin(dv)], 1);
    // K'[k=b][c=t] = exp(-C/eps)*2^13; half index = ((k>>3)*256 + c)*8 + (k&7)
    float kv = __expf(-dv * (1.f / EPS) + KSCALE_LN);
    Kh[(((b >> 3) * 256 + t) << 3) + (b & 7)] = (f16)kv;
}

// ---------------- k_sink: median + prep prologue, R6-proven MFMA loop, fused finalize ----------------
// 256 blocks x 512 thr, 3 problems/block. K frag = 16 uint4 = 64 VGPR pinned (R6-proven
// no-spill shape). One barrier per half-step: quad0 lanes keep z in regs, EL in regs,
// write u' to the other U buffer. Duals df/dg live in quad0 regs.
union __align__(16) SP {
    float PW[4][3][256];     // [0]=Pa [1]=Pb [2]=ELa [3]=ELb (post-median)
    float cand[2][CCAP];     // median candidates (pre-prep)
};

__device__ __forceinline__ void prep_row(bool isOrig, int i, float i2o, float i2l,
                                         const float* __restrict__ Do,
                                         const float* __restrict__ part2,
                                         float* Pdst, float* Edst,
                                         float* rsum, int t) {
    float sv = 0.f;
    if (t < 256) {
        float d = isOrig ? Do[i * 256 + t] : fmaxf(1.f - part2[i * 256 + t], 0.f);
        float ii = isOrig ? i2o : i2l;
        sv = (i == t) ? 0.f : __expf(-d * d * ii);
    }
    float wsm = wave_red_sum(sv);
    if ((t & 63) == 0) rsum[t >> 6] = wsm;
    __syncthreads();
    float tot = rsum[0] + rsum[1] + rsum[2] + rsum[3];
    if (t < 256) {
        float pv = sv / fmaxf(tot, 1e-8f);
        Pdst[t] = pv;
        Edst[t] = EPS * __logf(fmaxf(pv, 1e-8f)) + EPS * KSCALE_LN;
    }
    __syncthreads();
}

__global__ __launch_bounds__(512, 2) void k_sink(const float* __restrict__ lsl,
                                                 const float* __restrict__ lvr,
                                                 const float* __restrict__ lvt,
                                                 float* __restrict__ out,
                                                 float* __restrict__ ws) {
    __shared__ SP sp;
    __shared__ __align__(16) f16 U[2176];     // 2 buffers x 4 rows x 272 halfs
    __shared__ float rsum[8];
    __shared__ int redci[8];
    __shared__ int binsel[2], krel[2], ccnt[2];
    __shared__ float mres[2];
    __shared__ float CW[8][3];
    int t = threadIdx.x;
    int lane = t & 63, wv = t >> 6, m16 = lane & 15, quad = lane >> 4;
    int b = blockIdx.x;
    int cA = 32 * wv + m16, cB = cA + 16;

    float* acc = ws;
    const int* hist = (const int*)(ws + WS_HIST);
    const float* Do = ws + WS_DO;
    const uint4* Kq = (const uint4*)(ws + WS_KH);
    const float* part2 = ws + WS_PART2;

    // ---- median: hist scan (redundant per block) ----
    {
        int chunk = t * 16, s16 = 0;
        #pragma unroll
        for (int j = 0; j < 16; j++) s16 += hist[chunk + j];
        int inc = s16;
        #pragma unroll
        for (int o = 1; o < 64; o <<= 1) {
            int vv = __shfl_up(inc, o, 64);
            if (lane >= o) inc += vv;
        }
        if (lane == 63) redci[wv] = inc;
        if (t < 2) ccnt[t] = 0;
        __syncthreads();
        int woff = 0;
        for (int i = 0; i < wv; i++) woff += redci[i];
        int excl = woff + inc - s16;
        for (int sel = 0; sel < 2; sel++) {
            int k = 32767 + sel;
            if (excl <= k && k < excl + s16) {
                int cum = excl; bool found = false;
                for (int j = 0; j < 16; j++) {
                    int hc = hist[chunk + j];
                    if (!found) {
                        if (cum + hc > k) { binsel[sel] = chunk + j; krel[sel] = k - cum; found = true; }
                        else cum += hc;
                    }
                }
            }
        }
        __syncthreads();
    }
    // ---- candidates + exact selection ----
    {
        int bin0 = binsel[0], bin1 = binsel[1];
        for (int i2 = 0; i2 < 128; i2++) {
            float dv = Do[t + i2 * 512];
            int bb = med_bin(dv);
            if (bb == bin0) { int ix = atomicAdd(&ccnt[0], 1); if (ix < CCAP) sp.cand[0][ix] = dv; }
            if (bb == bin1) { int ix = atomicAdd(&ccnt[1], 1); if (ix < CCAP) sp.cand[1][ix] = dv; }
        }
        if (t == 0) {
            mres[0] = ((float)bin0 + 0.5f) * (1.f / 4096.f);
            mres[1] = ((float)bin1 + 0.5f) * (1.f / 4096.f);
        }
        __syncthreads();
        for (int sel = 0; sel < 2; sel++) {
            int M = (ccnt[sel] <= CCAP) ? ccnt[sel] : 0;
            int kr = krel[sel];
            for (int ci = t; ci < M; ci += 512) {
                float x = sp.cand[sel][ci];
                int L = 0, E = 0;
                for (int j = 0; j < M; j++) {
                    float v = sp.cand[sel][j];
                    L += (v < x) ? 1 : 0;
                    E += (v == x) ? 1 : 0;
                }
                if (L <= kr && kr < L + E) mres[sel] = x;
            }
        }
        __syncthreads();
    }
    float sg = 0.5f * (mres[0] + mres[1]);
    if (sg == 0.f) sg = 1e-6f;
    float i2o = 1.f / (2.f * sg * sg);
    float xs = lsl[0];
    float spv = (xs > 20.f) ? xs : log1pf(__expf(xs));
    float sgl = spv + 1e-6f;
    float i2l = 1.f / (2.f * sgl * sgl);
    __syncthreads();   // cand reads done before PW overwrite

    // ---- prep this block's 6 rows into PW ----
    #pragma unroll
    for (int p = 0; p < 3; p++) {
        int r = b * 3 + p, s = r >> 8, i = r & 255;
        prep_row(s != 1, i, i2o, i2l, Do, part2, &sp.PW[0][p][0], &sp.PW[2][p][0], rsum, t);
        prep_row(s == 2, i, i2o, i2l, Do, part2, &sp.PW[1][p][0], &sp.PW[3][p][0], rsum, t);
    }

    // ---- K fragments (R6-proven 64-VGPR shape) ----
    uint4 bf0[8], bf1[8];
    #pragma unroll
    for (int kc = 0; kc < 8; kc++) {
        bf0[kc] = Kq[(kc * 4 + quad) * 256 + cA];
        bf1[kc] = Kq[(kc * 4 + quad) * 256 + cB];
    }
    #pragma unroll
    for (int kc = 0; kc < 8; kc++) { PIN_U4(bf0[kc]); PIN_U4(bf1[kc]); }

    // quad0 EL registers
    float elA[3][2] = {}, elB[3][2] = {}, df[3][2] = {}, dg[3][2] = {};
    if (quad == 0) {
        #pragma unroll
        for (int p = 0; p < 3; p++) {
            elA[p][0] = sp.PW[2][p][cA]; elA[p][1] = sp.PW[2][p][cB];
            elB[p][0] = sp.PW[3][p][cA]; elB[p][1] = sp.PW[3][p][cB];
        }
    }
    // init both U buffers to 1.0 (row 3 = permanent finite dummy)
    if (t < 272)
        *(uint4*)&U[t * 8] = make_uint4(0x3C003C00u, 0x3C003C00u, 0x3C003C00u, 0x3C003C00u);
    __syncthreads();

    // ---- main loop: 1 barrier per half-step ----
    for (int it = 0; it < 2 * SINK_ITERS; it++) {
        const f16* ub = U + (it & 1) * 1088;
        f16* un = U + ((it + 1) & 1) * 1088;
        f32x4 a0 = {0.f, 0.f, 0.f, 0.f}, a1 = {0.f, 0.f, 0.f, 0.f};
        #pragma unroll
        for (int kc = 0; kc < 8; kc++) {
            f16x8 a = *(const f16x8*)&ub[(m16 & 3) * 272 + kc * 32 + quad * 8];
            a0 = __builtin_amdgcn_mfma_f32_16x16x32_f16(a, __builtin_bit_cast(f16x8, bf0[kc]), a0, 0, 0, 0);
            a1 = __builtin_amdgcn_mfma_f32_16x16x32_f16(a, __builtin_bit_cast(f16x8, bf1[kc]), a1, 0, 0, 0);
        }
        if (quad == 0) {   // C/D rows 0..3 live on quad0; rows 0..2 = problems
            bool fs = (it & 1) != 0;
            #pragma unroll
            for (int p = 0; p < 3; p++) {
                float e0 = fs ? elA[p][0] : elB[p][0];
                float e1 = fs ? elA[p][1] : elB[p][1];
                float d0 = e0 - EPS * __logf(a0[p]);
                float d1 = e1 - EPS * __logf(a1[p]);
                if (fs) { df[p][0] = d0; df[p][1] = d1; }
                else    { dg[p][0] = d0; dg[p][1] = d1; }
                un[p * 272 + cA] = (f16)__expf(d0);
                un[p * 272 + cB] = (f16)__expf(d1);
            }
        }
        __syncthreads();
    }

    // ---- cost: quad0 lanes cover all 256 cols exactly once ----
    float cs[3] = {};
    if (quad == 0) {
        #pragma unroll
        for (int p = 0; p < 3; p++)
            cs[p] = sp.PW[0][p][cA] * df[p][0] + sp.PW[1][p][cA] * dg[p][0] +
                    sp.PW[0][p][cB] * df[p][1] + sp.PW[1][p][cB] * dg[p][1];
    }
    #pragma unroll
    for (int p = 0; p < 3; p++) {
        float v = wave_red_sum(cs[p]);
        if (lane == 0) CW[wv][p] = v;
    }
    __syncthreads();
    if (t < 3) {
        float s = 0.f;
        for (int w2 = 0; w2 < 8; w2++) s += CW[w2][t];
        atomicAdd(&acc[(b * 3 + t) >> 8], s);
    }
    __syncthreads();

    // ---- fused finalize: last block to finish computes the output ----
    if (t == 0) {
        __threadfence();
        unsigned old = atomicAdd((unsigned*)&acc[8], 1u);
        if (old == 255u) {
            float recon = atomicAdd(&acc[3], 0.f) * (1.f / (256.f * 4096.f));
            float ot0 = atomicAdd(&acc[0], 0.f) * (1.f / 256.f);
            float ot1 = atomicAdd(&acc[1], 0.f) * (1.f / 256.f);
            float ot2 = atomicAdd(&acc[2], 0.f) * (1.f / 256.f);
            float topo = fmaxf(ot0 - 0.5f * ot1 - 0.5f * ot2, 0.f);
            float a = lvr[0], c = lvt[0];
            out[0] = 0.5f * __expf(-a) * recon + 0.5f * a +
                     0.5f * __expf(-c) * topo + 0.5f * c;
            out[1] = recon;
            out[2] = topo;
        }
    }
}

extern "C" void kernel_launch(void* const* d_in, const int* in_sizes, int n_in,
                              void* d_out, int out_size, void* d_ws, size_t ws_size,
                              hipStream_t stream) {
    const float4* xo4 = (const float4*)d_in[0];
    const float4* xr4 = (const float4*)d_in[1];
    const float4* z4  = (const float4*)d_in[2];
    const float* lsl = (const float*)d_in[3];
    const float* lvr = (const float*)d_in[4];
    const float* lvt = (const float*)d_in[5];
    float* out = (float*)d_out;
    float* ws = (float*)d_ws;

    // zero acc (incl. done counter) + hist
    hipMemsetAsync(ws, 0, 8320 * sizeof(float), stream);
    k_pre<<<256, 512, 0, stream>>>(xo4, xr4, z4, ws);
    k_gemm<<<272, 512, 0, stream>>>(ws);
    k_mid<<<256, 256, 0, stream>>>(ws);
    k_sink<<<256, 512, 0, stream>>>(lsl, lvr, lvt, out, ws);
}